// Round 7
// baseline (436.489 us; speedup 1.0000x reference)
//
#include <hip/hip_runtime.h>
#include <stdint.h>

#define NB 32
#define W 512
#define H 512
#define TX 54          // output cols per block (region = 64 = one wave)
#define TY 32          // output rows per block (4 waves x 8-row chunks)
#define BLOCK 256
#define SP 65          // LDS pitch in dwords: 65%32=1 -> <=2-way banks (free)
#define GRIDX 10       // ceil(512/54)
#define C2f 0.0009f

// normalized gaussian(11, sigma=1.5)
#define GW0 0.001028381f
#define GW1 0.007598758f
#define GW2 0.036000773f
#define GW3 0.109360700f
#define GW4 0.213005540f
#define GW5 0.266011720f

__device__ __forceinline__ float gwv(int k) {
    const float g[11] = {GW0, GW1, GW2, GW3, GW4, GW5, GW4, GW3, GW2, GW1, GW0};
    return g[k];
}

typedef __fp16 fp16x2 __attribute__((ext_vector_type(2)));

__device__ __forceinline__ uint32_t pk2(float a, float b) {
    fp16x2 h = __builtin_amdgcn_cvt_pkrtz(a, b);   // v_cvt_pkrtz_f16_f32: 1 instr
    union { fp16x2 h; uint32_t u; } cv; cv.h = h; return cv.u;
}
__device__ __forceinline__ float lo16(uint32_t u) {
    union { uint32_t u; fp16x2 h; } cv; cv.u = u; return (float)cv.h.x;
}
__device__ __forceinline__ float hi16(uint32_t u) {
    union { uint32_t u; fp16x2 h; } cv; cv.u = u; return (float)cv.h.y;
}

// LDS: everything f16-packed, 2 values per dword.
struct SM {
    uint32_t pA[42][SP];    // pack(g, i)   rows y0-5 .. y0+36
    uint32_t pB[42][SP];    // pack(v, g)
    uint32_t scrA[TY][SP];  // vpass out, pack(q0, q1)
    uint32_t scrB[TY][SP];  // vpass out, pack(q2, q3)
    float red[3][4];
};                          // 148*65*4 + 48 = 38528 B -> 4 blocks/CU

template<bool GUARD>
__device__ __forceinline__ float ld(const float* __restrict__ p, int gy, int gx) {
    if (GUARD) {
        bool ok = ((unsigned)gx < W) && ((unsigned)gy < H);
        int cy = min(max(gy, 0), H - 1);
        int cx = min(max(gx, 0), W - 1);
        float v = p[cy * W + cx];
        return ok ? v : 0.f;  // zero-pad semantics
    }
    return p[gy * W + gx];
}

// Vertical 11-tap gaussian from packed LDS, circular register window.
// PH 0 (reads pA: x=g, y=i): q0=mu1, q1=mu2, q2=c22(ii), q3=c12(gi)
// PH 1 (reads pB: x=v, y=g): q0=mu3, q1=c11(gg), q2=c33(vv), q3=c13(gv)
template<int PH>
__device__ __forceinline__ void vpass(SM& sm, int lane, int wvi) {
    const int base = 8 * wvi;
    const uint32_t (*src)[SP] = (PH == 0) ? sm.pA : sm.pB;
    float xa[11], xb[11];
    #pragma unroll
    for (int k = 0; k < 10; ++k) {
        uint32_t u = src[base + k][lane];
        xa[k] = lo16(u); xb[k] = hi16(u);
    }
    #pragma unroll
    for (int r = 0; r < 8; ++r) {
        uint32_t u = src[base + 10 + r][lane];
        const int i10 = (r + 10) % 11;
        xa[i10] = lo16(u); xb[i10] = hi16(u);
        float q0 = 0.f, q1 = 0.f, q2 = 0.f, q3 = 0.f;
        #pragma unroll
        for (int k = 0; k < 11; ++k) {
            float x = xa[(r + k) % 11], y = xb[(r + k) % 11], g = gwv(k);
            if (PH == 0) {
                q0 = fmaf(g, x, q0);
                q1 = fmaf(g, y, q1);
                q2 = fmaf(g, y * y, q2);
                q3 = fmaf(g, x * y, q3);
            } else {
                q0 = fmaf(g, x, q0);
                q1 = fmaf(g, y * y, q1);
                q2 = fmaf(g, x * x, q2);
                q3 = fmaf(g, x * y, q3);
            }
        }
        sm.scrA[base + r][lane] = pk2(q0, q1);
        sm.scrB[base + r][lane] = pk2(q2, q3);
    }
}

// Horizontal 11-tap on packed scr: thread owns (row, 7-output chunk); chunk 7
// clamps to xb=47 (reads < 64); its j<2 outputs are duplicates, masked later.
__device__ __forceinline__ void hpass(SM& sm, float (&res)[4][7], int tid) {
    const int r = tid & 31, cch = tid >> 5;
    const int xb = (cch < 7) ? cch * 7 : 47;
    float w0[11], w1[11], w2[11], w3[11];
    #pragma unroll
    for (int k = 0; k < 10; ++k) {
        uint32_t uA = sm.scrA[r][xb + k], uB = sm.scrB[r][xb + k];
        w0[k] = lo16(uA); w1[k] = hi16(uA);
        w2[k] = lo16(uB); w3[k] = hi16(uB);
    }
    #pragma unroll
    for (int j = 0; j < 7; ++j) {
        uint32_t uA = sm.scrA[r][xb + 10 + j], uB = sm.scrB[r][xb + 10 + j];
        const int i10 = (j + 10) % 11;
        w0[i10] = lo16(uA); w1[i10] = hi16(uA);
        w2[i10] = lo16(uB); w3[i10] = hi16(uB);
        float a0 = 0.f, a1 = 0.f, a2 = 0.f, a3 = 0.f;
        #pragma unroll
        for (int k = 0; k < 11; ++k) {
            const int s = (j + k) % 11;
            const float g = gwv(k);
            a0 = fmaf(g, w0[s], a0);
            a1 = fmaf(g, w1[s], a1);
            a2 = fmaf(g, w2[s], a2);
            a3 = fmaf(g, w3[s], a3);
        }
        res[0][j] = a0; res[1][j] = a1; res[2][j] = a2; res[3][j] = a3;
    }
}

__device__ __forceinline__ float mag3(const float m[3][3], int s0, int s1, int s2) {
    float sgx = (m[s0][2] - m[s0][0]) + 2.f * (m[s1][2] - m[s1][0]) +
                (m[s2][2] - m[s2][0]);
    float sgy = (m[s0][0] - m[s2][0]) + 2.f * (m[s0][1] - m[s2][1]) +
                (m[s0][2] - m[s2][2]);
    return fabsf(sgx) + fabsf(sgy);
}

template<bool GUARD>
__device__ __forceinline__ void body(
    const float* __restrict__ pv, const float* __restrict__ pi,
    const float* __restrict__ pg, SM& sm,
    int x0, int y0, double* __restrict__ sums) {
    const int tid = threadIdx.x;
    const int lane = tid & 63;
    const int wvi = tid >> 6;
    const int gx = x0 - 5 + lane;
    const bool colok = (lane >= 5) && (lane <= 58) && (!GUARD || gx < W);
    float sum_in = 0.f, sum_grad = 0.f, sum_ssim = 0.f;

    // ---- stage: global read ONCE, pack f16 pairs to LDS; f32 intensity ----
    #pragma unroll
    for (int k = 0; k < 11; ++k) {
        int r = wvi + 4 * k;
        if (r < 42) {
            int gy = y0 - 5 + r;
            float g = ld<GUARD>(pg, gy, gx);
            float i = ld<GUARD>(pi, gy, gx);
            float v = ld<GUARD>(pv, gy, gx);
            sm.pA[r][lane] = pk2(g, i);
            sm.pB[r][lane] = pk2(v, g);
            if (colok && r >= 5 && r <= 36)
                sum_in += fabsf(g - fmaxf(v, i));
        }
    }
    __syncthreads();

    // ---- sobel + grad loss from packed LDS (throughput reads, no chains) ----
    {
        const int c = min(max(lane, 1), 62);
        const int base = 8 * wvi + 4;
        float fg[3][3], fi[3][3], fv[3][3];
        #pragma unroll
        for (int k = 0; k < 2; ++k) {
            #pragma unroll
            for (int dx = 0; dx < 3; ++dx) {
                uint32_t ua = sm.pA[base + k][c - 1 + dx];
                uint32_t ub = sm.pB[base + k][c - 1 + dx];
                fg[k][dx] = lo16(ua); fi[k][dx] = hi16(ua); fv[k][dx] = lo16(ub);
            }
        }
        #pragma unroll
        for (int j = 0; j < 8; ++j) {
            const int s2 = (j + 2) % 3, s0 = j % 3, s1 = (j + 1) % 3;
            #pragma unroll
            for (int dx = 0; dx < 3; ++dx) {
                uint32_t ua = sm.pA[base + 2 + j][c - 1 + dx];
                uint32_t ub = sm.pB[base + 2 + j][c - 1 + dx];
                fg[s2][dx] = lo16(ua); fi[s2][dx] = hi16(ua); fv[s2][dx] = lo16(ub);
            }
            float mg = mag3(fg, s0, s1, s2);
            float mi = mag3(fi, s0, s1, s2);
            float mv = mag3(fv, s0, s1, s2);
            if (colok) sum_grad += fabsf(mg - fmaxf(mv, mi));
        }
    }
    // no barrier: vpass<0> reads pA (read-read with sobel), writes scr only

    float resA[4][7], resB[4][7];
    vpass<0>(sm, lane, wvi);
    __syncthreads();
    hpass(sm, resA, tid);          // {mu1, mu2, c22, c12}
    __syncthreads();
    vpass<1>(sm, lane, wvi);
    __syncthreads();
    hpass(sm, resB, tid);          // {mu3, c11, c33, c13}

    // ---- ssim map ----
    const int cch = tid >> 5;
    const int xb = (cch < 7) ? cch * 7 : 47;
    #pragma unroll
    for (int j = 0; j < 7; ++j) {
        bool valid = (cch < 7) || (j >= 2);     // drop chunk-7 duplicates
        if (GUARD) valid = valid && (x0 + xb + j < W);
        float m1 = resA[0][j], m2 = resA[1][j], m3 = resB[0][j];
        float sig1 = resB[1][j] - m1 * m1;
        float sig2 = resA[2][j] - m2 * m2;
        float sig3 = resB[2][j] - m3 * m3;
        float sg12 = resA[3][j] - m1 * m2;
        float sg13 = resB[3][j] - m1 * m3;
        float x2 = sqrtf(sig2);
        float x3 = sqrtf(sig3);
        float map12 = (2.f * sg12 + C2f) / (sig1 + sig2 + C2f);
        float map13 = (2.f * sg13 + C2f) / (sig1 + sig3 + C2f);
        // matches jnp.where(|x2| >= |x3|, map12, map13); NaN -> map13
        float m = (fabsf(x2) >= fabsf(x3)) ? map12 : map13;
        if (valid) sum_ssim += m;
    }

    // ---- reduce ----
    #pragma unroll
    for (int o = 32; o > 0; o >>= 1) {
        sum_in   += __shfl_down(sum_in, o);
        sum_grad += __shfl_down(sum_grad, o);
        sum_ssim += __shfl_down(sum_ssim, o);
    }
    if (lane == 0) { sm.red[0][wvi] = sum_in; sm.red[1][wvi] = sum_grad; sm.red[2][wvi] = sum_ssim; }
    __syncthreads();
    if (tid == 0) {
        float a = 0.f, b = 0.f, c = 0.f;
        #pragma unroll
        for (int k = 0; k < 4; ++k) { a += sm.red[0][k]; b += sm.red[1][k]; c += sm.red[2][k]; }
        atomicAdd(&sums[0], (double)a);
        atomicAdd(&sums[1], (double)b);
        atomicAdd(&sums[2], (double)c);
    }
}

__global__ __launch_bounds__(BLOCK, 4) void fusion_main(
    const float* __restrict__ vis, const float* __restrict__ ir,
    const float* __restrict__ gen, double* __restrict__ sums) {
    __shared__ SM sm;
    const size_t off = (size_t)blockIdx.z * (H * W);
    const int x0 = blockIdx.x * TX;
    const int y0 = blockIdx.y * TY;
    const float* pv = vis + off;
    const float* pi = ir + off;
    const float* pg = gen + off;
    bool interior = (blockIdx.x >= 1) && (blockIdx.x <= 8) &&
                    (blockIdx.y >= 1) && (blockIdx.y <= 14);
    if (interior) body<false>(pv, pi, pg, sm, x0, y0, sums);
    else          body<true>(pv, pi, pg, sm, x0, y0, sums);
}

__global__ void finalize(const double* __restrict__ sums, float* __restrict__ out) {
    const double inv = 1.0 / ((double)NB * H * W);
    out[0] = (float)(1.5 * sums[0] * inv);
    out[1] = (float)(0.5 * (1.0 - sums[2] * inv) + sums[1] * inv);
}

extern "C" void kernel_launch(void* const* d_in, const int* in_sizes, int n_in,
                              void* d_out, int out_size, void* d_ws, size_t ws_size,
                              hipStream_t stream) {
    const float* vis = (const float*)d_in[0];
    const float* ir  = (const float*)d_in[1];
    const float* gen = (const float*)d_in[2];
    float* out = (float*)d_out;
    double* sums = (double*)d_ws;

    (void)hipMemsetAsync(d_ws, 0, 3 * sizeof(double), stream);
    dim3 grid(GRIDX, H / TY, NB);
    fusion_main<<<grid, BLOCK, 0, stream>>>(vis, ir, gen, sums);
    finalize<<<1, 1, 0, stream>>>(sums, out);
}

// Round 8
// 309.175 us; speedup vs baseline: 1.4118x; 1.4118x over previous
//
#include <hip/hip_runtime.h>
#include <stdint.h>

#define NB 32
#define W 512
#define H 512
#define TX 54          // output cols per block (region = 64 = one wave)
#define TY 32          // output rows per block (4 waves x 8-row chunks)
#define BLOCK 256
#define SP 65          // LDS pitch in dwords: 65%32=1 -> <=2-way banks (free)
#define GRIDX 10       // ceil(512/54)
#define C2f 0.0009f

// normalized gaussian(11, sigma=1.5)
#define GW0 0.001028381f
#define GW1 0.007598758f
#define GW2 0.036000773f
#define GW3 0.109360700f
#define GW4 0.213005540f
#define GW5 0.266011720f

__device__ __forceinline__ float gwv(int k) {
    const float g[11] = {GW0, GW1, GW2, GW3, GW4, GW5, GW4, GW3, GW2, GW1, GW0};
    return g[k];
}

typedef __fp16 fp16x2 __attribute__((ext_vector_type(2)));

__device__ __forceinline__ uint32_t pk2(float a, float b) {
    fp16x2 h = __builtin_amdgcn_cvt_pkrtz(a, b);   // v_cvt_pkrtz_f16_f32: 1 instr
    union { fp16x2 h; uint32_t u; } cv; cv.h = h; return cv.u;
}
__device__ __forceinline__ float lo16(uint32_t u) {
    union { uint32_t u; fp16x2 h; } cv; cv.u = u; return (float)cv.h.x;
}
__device__ __forceinline__ float hi16(uint32_t u) {
    union { uint32_t u; fp16x2 h; } cv; cv.u = u; return (float)cv.h.y;
}

// LDS: everything f16-packed, 2 values per dword.
struct SM {
    uint32_t pA[42][SP];    // pack(g, i)   rows y0-5 .. y0+36
    uint32_t pB[42][SP];    // pack(v, g)
    uint32_t scrA[TY][SP];  // vpass out, pack(q0, q1)
    uint32_t scrB[TY][SP];  // vpass out, pack(q2, q3)
    float red[3][4];
};                          // 148*65*4 + 48 = 38528 B -> 4 blocks/CU

template<bool GUARD>
__device__ __forceinline__ float ld(const float* __restrict__ p, int gy, int gx) {
    if (GUARD) {
        bool ok = ((unsigned)gx < W) && ((unsigned)gy < H);
        int cy = min(max(gy, 0), H - 1);
        int cx = min(max(gx, 0), W - 1);
        float v = p[cy * W + cx];
        return ok ? v : 0.f;  // zero-pad semantics
    }
    return p[gy * W + gx];
}

// Vertical 11-tap gaussian from packed LDS, circular register window.
// PH 0 (reads pA: x=g, y=i): q0=mu1, q1=mu2, q2=c22(ii), q3=c12(gi)
// PH 1 (reads pB: x=v, y=g): q0=mu3, q1=c11(gg), q2=c33(vv), q3=c13(gv)
template<int PH>
__device__ __forceinline__ void vpass(SM& sm, int lane, int wvi) {
    const int base = 8 * wvi;
    const uint32_t (*src)[SP] = (PH == 0) ? sm.pA : sm.pB;
    float xa[11], xb[11];
    #pragma unroll
    for (int k = 0; k < 10; ++k) {
        uint32_t u = src[base + k][lane];
        xa[k] = lo16(u); xb[k] = hi16(u);
    }
    #pragma unroll
    for (int r = 0; r < 8; ++r) {
        uint32_t u = src[base + 10 + r][lane];
        const int i10 = (r + 10) % 11;
        xa[i10] = lo16(u); xb[i10] = hi16(u);
        float q0 = 0.f, q1 = 0.f, q2 = 0.f, q3 = 0.f;
        #pragma unroll
        for (int k = 0; k < 11; ++k) {
            float x = xa[(r + k) % 11], y = xb[(r + k) % 11], g = gwv(k);
            if (PH == 0) {
                q0 = fmaf(g, x, q0);
                q1 = fmaf(g, y, q1);
                q2 = fmaf(g, y * y, q2);
                q3 = fmaf(g, x * y, q3);
            } else {
                q0 = fmaf(g, x, q0);
                q1 = fmaf(g, y * y, q1);
                q2 = fmaf(g, x * x, q2);
                q3 = fmaf(g, x * y, q3);
            }
        }
        sm.scrA[base + r][lane] = pk2(q0, q1);
        sm.scrB[base + r][lane] = pk2(q2, q3);
    }
}

// Horizontal 11-tap on packed scr: thread owns (row, 7-output chunk); chunk 7
// clamps to xb=47 (reads < 64); its j<2 outputs are duplicates, masked later.
__device__ __forceinline__ void hpass(SM& sm, float (&res)[4][7], int tid) {
    const int r = tid & 31, cch = tid >> 5;
    const int xb = (cch < 7) ? cch * 7 : 47;
    float w0[11], w1[11], w2[11], w3[11];
    #pragma unroll
    for (int k = 0; k < 10; ++k) {
        uint32_t uA = sm.scrA[r][xb + k], uB = sm.scrB[r][xb + k];
        w0[k] = lo16(uA); w1[k] = hi16(uA);
        w2[k] = lo16(uB); w3[k] = hi16(uB);
    }
    #pragma unroll
    for (int j = 0; j < 7; ++j) {
        uint32_t uA = sm.scrA[r][xb + 10 + j], uB = sm.scrB[r][xb + 10 + j];
        const int i10 = (j + 10) % 11;
        w0[i10] = lo16(uA); w1[i10] = hi16(uA);
        w2[i10] = lo16(uB); w3[i10] = hi16(uB);
        float a0 = 0.f, a1 = 0.f, a2 = 0.f, a3 = 0.f;
        #pragma unroll
        for (int k = 0; k < 11; ++k) {
            const int s = (j + k) % 11;
            const float g = gwv(k);
            a0 = fmaf(g, w0[s], a0);
            a1 = fmaf(g, w1[s], a1);
            a2 = fmaf(g, w2[s], a2);
            a3 = fmaf(g, w3[s], a3);
        }
        res[0][j] = a0; res[1][j] = a1; res[2][j] = a2; res[3][j] = a3;
    }
}

__device__ __forceinline__ float mag3(const float m[3][3], int s0, int s1, int s2) {
    float sgx = (m[s0][2] - m[s0][0]) + 2.f * (m[s1][2] - m[s1][0]) +
                (m[s2][2] - m[s2][0]);
    float sgy = (m[s0][0] - m[s2][0]) + 2.f * (m[s0][1] - m[s2][1]) +
                (m[s0][2] - m[s2][2]);
    return fabsf(sgx) + fabsf(sgy);
}

template<bool GUARD>
__device__ __forceinline__ void body(
    const float* __restrict__ pv, const float* __restrict__ pi,
    const float* __restrict__ pg, SM& sm,
    int x0, int y0, double* __restrict__ sums) {
    const int tid = threadIdx.x;
    const int lane = tid & 63;
    const int wvi = tid >> 6;
    const int gx = x0 - 5 + lane;
    const bool colok = (lane >= 5) && (lane <= 58) && (!GUARD || gx < W);
    float sum_in = 0.f, sum_grad = 0.f, sum_ssim = 0.f;

    // ---- stage: global read ONCE, pack f16 pairs to LDS; f32 intensity ----
    #pragma unroll
    for (int k = 0; k < 11; ++k) {
        int r = wvi + 4 * k;
        if (r < 42) {
            int gy = y0 - 5 + r;
            float g = ld<GUARD>(pg, gy, gx);
            float i = ld<GUARD>(pi, gy, gx);
            float v = ld<GUARD>(pv, gy, gx);
            sm.pA[r][lane] = pk2(g, i);
            sm.pB[r][lane] = pk2(v, g);
            if (colok && r >= 5 && r <= 36)
                sum_in += fabsf(g - fmaxf(v, i));
        }
    }
    __syncthreads();

    // ---- sobel + grad loss from packed LDS (throughput reads, no chains) ----
    {
        const int c = min(max(lane, 1), 62);
        const int base = 8 * wvi + 4;
        float fg[3][3], fi[3][3], fv[3][3];
        #pragma unroll
        for (int k = 0; k < 2; ++k) {
            #pragma unroll
            for (int dx = 0; dx < 3; ++dx) {
                uint32_t ua = sm.pA[base + k][c - 1 + dx];
                uint32_t ub = sm.pB[base + k][c - 1 + dx];
                fg[k][dx] = lo16(ua); fi[k][dx] = hi16(ua); fv[k][dx] = lo16(ub);
            }
        }
        #pragma unroll
        for (int j = 0; j < 8; ++j) {
            const int s2 = (j + 2) % 3, s0 = j % 3, s1 = (j + 1) % 3;
            #pragma unroll
            for (int dx = 0; dx < 3; ++dx) {
                uint32_t ua = sm.pA[base + 2 + j][c - 1 + dx];
                uint32_t ub = sm.pB[base + 2 + j][c - 1 + dx];
                fg[s2][dx] = lo16(ua); fi[s2][dx] = hi16(ua); fv[s2][dx] = lo16(ub);
            }
            float mg = mag3(fg, s0, s1, s2);
            float mi = mag3(fi, s0, s1, s2);
            float mv = mag3(fv, s0, s1, s2);
            if (colok) sum_grad += fabsf(mg - fmaxf(mv, mi));
        }
    }
    // no barrier: vpass<0> reads pA (read-read with sobel), writes scr only

    float resA[4][7], resB[4][7];
    vpass<0>(sm, lane, wvi);
    __syncthreads();
    hpass(sm, resA, tid);          // {mu1, mu2, c22, c12}
    __syncthreads();
    vpass<1>(sm, lane, wvi);
    __syncthreads();
    hpass(sm, resB, tid);          // {mu3, c11, c33, c13}

    // ---- ssim map ----
    const int cch = tid >> 5;
    const int xb = (cch < 7) ? cch * 7 : 47;
    #pragma unroll
    for (int j = 0; j < 7; ++j) {
        bool valid = (cch < 7) || (j >= 2);     // drop chunk-7 duplicates
        if (GUARD) valid = valid && (x0 + xb + j < W);
        float m1 = resA[0][j], m2 = resA[1][j], m3 = resB[0][j];
        float sig1 = resB[1][j] - m1 * m1;
        float sig2 = resA[2][j] - m2 * m2;
        float sig3 = resB[2][j] - m3 * m3;
        float sg12 = resA[3][j] - m1 * m2;
        float sg13 = resB[3][j] - m1 * m3;
        float x2 = sqrtf(sig2);
        float x3 = sqrtf(sig3);
        float map12 = (2.f * sg12 + C2f) / (sig1 + sig2 + C2f);
        float map13 = (2.f * sg13 + C2f) / (sig1 + sig3 + C2f);
        // matches jnp.where(|x2| >= |x3|, map12, map13); NaN -> map13
        float m = (fabsf(x2) >= fabsf(x3)) ? map12 : map13;
        if (valid) sum_ssim += m;
    }

    // ---- reduce ----
    #pragma unroll
    for (int o = 32; o > 0; o >>= 1) {
        sum_in   += __shfl_down(sum_in, o);
        sum_grad += __shfl_down(sum_grad, o);
        sum_ssim += __shfl_down(sum_ssim, o);
    }
    if (lane == 0) { sm.red[0][wvi] = sum_in; sm.red[1][wvi] = sum_grad; sm.red[2][wvi] = sum_ssim; }
    __syncthreads();
    if (tid == 0) {
        float a = 0.f, b = 0.f, c = 0.f;
        #pragma unroll
        for (int k = 0; k < 4; ++k) { a += sm.red[0][k]; b += sm.red[1][k]; c += sm.red[2][k]; }
        atomicAdd(&sums[0], (double)a);
        atomicAdd(&sums[1], (double)b);
        atomicAdd(&sums[2], (double)c);
    }
}

// NOTE: no min-waves clamp — r7's __launch_bounds__(256,4) forced VGPR=64 and
// spilled ~770 MB to scratch (WRITE_SIZE 0.4->333 MB). Natural alloc ~100-116
// VGPR gives the same 4 blocks/CU via the LDS limit, without spills.
__global__ __launch_bounds__(BLOCK) void fusion_main(
    const float* __restrict__ vis, const float* __restrict__ ir,
    const float* __restrict__ gen, double* __restrict__ sums) {
    __shared__ SM sm;
    const size_t off = (size_t)blockIdx.z * (H * W);
    const int x0 = blockIdx.x * TX;
    const int y0 = blockIdx.y * TY;
    const float* pv = vis + off;
    const float* pi = ir + off;
    const float* pg = gen + off;
    bool interior = (blockIdx.x >= 1) && (blockIdx.x <= 8) &&
                    (blockIdx.y >= 1) && (blockIdx.y <= 14);
    if (interior) body<false>(pv, pi, pg, sm, x0, y0, sums);
    else          body<true>(pv, pi, pg, sm, x0, y0, sums);
}

__global__ void finalize(const double* __restrict__ sums, float* __restrict__ out) {
    const double inv = 1.0 / ((double)NB * H * W);
    out[0] = (float)(1.5 * sums[0] * inv);
    out[1] = (float)(0.5 * (1.0 - sums[2] * inv) + sums[1] * inv);
}

extern "C" void kernel_launch(void* const* d_in, const int* in_sizes, int n_in,
                              void* d_out, int out_size, void* d_ws, size_t ws_size,
                              hipStream_t stream) {
    const float* vis = (const float*)d_in[0];
    const float* ir  = (const float*)d_in[1];
    const float* gen = (const float*)d_in[2];
    float* out = (float*)d_out;
    double* sums = (double*)d_ws;

    (void)hipMemsetAsync(d_ws, 0, 3 * sizeof(double), stream);
    dim3 grid(GRIDX, H / TY, NB);
    fusion_main<<<grid, BLOCK, 0, stream>>>(vis, ir, gen, sums);
    finalize<<<1, 1, 0, stream>>>(sums, out);
}